// Round 9
// baseline (639.539 us; speedup 1.0000x reference)
//
#include <hip/hip_runtime.h>
#include <stdint.h>

#define NB 2
#define NL 2048
#define NH 16
#define ND 64
// out: [B,H,L,S] f32, S = NL

typedef __attribute__((ext_vector_type(8))) short short8;
typedef __attribute__((ext_vector_type(4))) float f32x4;
typedef __attribute__((ext_vector_type(4))) unsigned short ushort4v;

__device__ __forceinline__ unsigned short f2bf_rne(float x) {
    union { float f; unsigned int u; } v; v.f = x;
    unsigned int r = v.u + 0x7fffu + ((v.u >> 16) & 1u);
    return (unsigned short)(r >> 16);
}
__device__ __forceinline__ float bf2f(unsigned short b) {
    union { unsigned int u; float f; } v; v.u = ((unsigned int)b) << 16;
    return v.f;
}

// ---------------- Kernel A: proj + bf16 hi/lo split, head-major SWIZZLED panels
__global__ __launch_bounds__(256) void proj_bf16_kernel(const float* __restrict__ x,
                                                        const float* __restrict__ W,
                                                        unsigned short* __restrict__ ph,
                                                        unsigned short* __restrict__ pl) {
    __shared__ float Wlds[ND * ND];   // [d][e]
    __shared__ float xs[128 * 68];    // [r][d], stride 68 floats
    const int blk = blockIdx.x;       // b*256 + h*16 + lc
    const int lc = blk & 15;
    const int h = (blk >> 4) & 15;
    const int b = blk >> 8;
    const int l0 = lc * 128;
    const int t = threadIdx.x;

    {
        const float4* src = (const float4*)(W + (size_t)h * ND * ND);
#pragma unroll
        for (int i = 0; i < 4; ++i)
            ((float4*)Wlds)[t + 256 * i] = src[t + 256 * i];
    }
    {
#pragma unroll
        for (int i = 0; i < 8; ++i) {
            const int idx = t + 256 * i;  // 0..2047
            const int r = idx >> 4, c = idx & 15;
            const float4 v = *(const float4*)(x + (((size_t)b * NL + l0 + r) * NH + h) * ND + c * 4);
            *(float4*)&xs[r * 68 + c * 4] = v;
        }
    }
    __syncthreads();

    const int e4 = (t & 15) * 4;
    const int rg = t >> 4;  // 0..15
    float acc[8][4] = {};
    for (int d = 0; d < ND; ++d) {
        const float4 w4 = *(const float4*)&Wlds[d * ND + e4];
#pragma unroll
        for (int it = 0; it < 8; ++it) {
            const float xv = xs[(rg + it * 16) * 68 + d];
            acc[it][0] += xv * w4.x; acc[it][1] += xv * w4.y;
            acc[it][2] += xv * w4.z; acc[it][3] += xv * w4.w;
        }
    }

    unsigned short* phh = ph + ((size_t)(b * NH + h) * NL + l0) * ND;
    unsigned short* pll = pl + ((size_t)(b * NH + h) * NL + l0) * ND;
#pragma unroll
    for (int it = 0; it < 8; ++it) {
        const int r = rg + it * 16;
        const int ep = e4 ^ ((r & 7) << 3);  // swizzled element position (8B-group safe)
        ushort4v hv, lv;
#pragma unroll
        for (int j = 0; j < 4; ++j) {
            const unsigned short hb = f2bf_rne(acc[it][j]);
            hv[j] = hb;
            lv[j] = f2bf_rne(acc[it][j] - bf2f(hb));
        }
        *(ushort4v*)&phh[(size_t)r * ND + ep] = hv;
        *(ushort4v*)&pll[(size_t)r * ND + ep] = lv;
    }
}

// ---------------- Kernel B: part[bh][chunk][e] = sum over 128 keys (f64, fixed order)
__global__ __launch_bounds__(256) void ksum_part_kernel(const float* __restrict__ key,
                                                        double* __restrict__ part) {
    __shared__ double red[4][64];
    const int blk = blockIdx.x;   // bh*16 + chunk
    const int chunk = blk & 15, bh = blk >> 4;
    const int b = bh >> 4, h = bh & 15;
    const int t = threadIdx.x;
    const int e = t & 63, sub = t >> 6;
    const float* base = key + ((size_t)b * NL * NH + h) * ND + e;
    double acc = 0.0;
    const int s0 = chunk * 128 + sub * 32;
    for (int s = s0; s < s0 + 32; ++s)
        acc += (double)base[(size_t)s * (NH * ND)];
    red[sub][e] = acc;
    __syncthreads();
    if (t < 64) {
        const double s2 = red[0][t] + red[1][t] + red[2][t] + red[3][t];
        part[(size_t)blk * 64 + t] = s2;
    }
}

// ---------------- Kernel C: reduce partials; v[b,h,d] = Wq . (Wk^T . xsum)  (f64)
__global__ __launch_bounds__(64) void prep_kernel(const double* __restrict__ part,
                                                  const float* __restrict__ Wq,
                                                  const float* __restrict__ Wk,
                                                  double* __restrict__ v) {
    __shared__ double xs[ND], ks[ND];
    const int bh = blockIdx.x;
    const int h = bh & 15;
    const int t = threadIdx.x;  // 0..63
    {
        double a = 0.0;
#pragma unroll
        for (int c = 0; c < 16; ++c) a += part[((size_t)bh * 16 + c) * 64 + t];
        xs[t] = a;
    }
    __syncthreads();
    {
        double acc = 0.0;
        const float* wk = Wk + (size_t)h * ND * ND + t;  // column t
        for (int d = 0; d < ND; ++d) acc += xs[d] * (double)wk[(size_t)d * ND];
        ks[t] = acc;
    }
    __syncthreads();
    {
        double acc = 0.0;
        const float* wq = Wq + (size_t)h * ND * ND + (size_t)t * ND;  // row t
        for (int e = 0; e < ND; ++e) acc += (double)wq[e] * ks[e];
        v[(size_t)bh * ND + t] = acc;
    }
}

// ---------------- Kernel D: invden[b,h,l] = 1 / (x_q . v)  (f64 exact)
__global__ __launch_bounds__(256) void den_kernel(const float* __restrict__ xq,
                                                  const double* __restrict__ v,
                                                  float* __restrict__ invden) {
    __shared__ double vs[ND];
    const int bh = blockIdx.x;
    const int b = bh >> 4, h = bh & 15;
    const int t = threadIdx.x;
    if (t < 64) vs[t] = v[(size_t)bh * ND + t];
    __syncthreads();
    const int l = blockIdx.y * 256 + t;
    const float* xp = xq + (((size_t)b * NL + l) * NH + h) * ND;
    double acc = 0.0;
#pragma unroll 8
    for (int d = 0; d < ND; ++d) acc += (double)xp[d] * vs[d];
    invden[(size_t)bh * NL + l] = (float)(1.0 / acc);
}

// ---------------- Kernel E: attn — MFMA + gload_lds staging + LDS-coalesced epilogue.
// DIAGNOSTIC build: grid.z = 4*32, bh = z&31 (4 identical rewrites) to force this
// dispatch into the rocprof top-5. Epilogue: acc -> swizzled 64KB f32 LDS tile
// (smem reuse) -> 512B-contiguous wave stores (T-E experiment).
__global__ __launch_bounds__(256) void attn_kernel(const unsigned short* __restrict__ qbh,
                                                   const unsigned short* __restrict__ qbl,
                                                   const unsigned short* __restrict__ kbh,
                                                   const unsigned short* __restrict__ kbl,
                                                   const float* __restrict__ invden,
                                                   float* __restrict__ out) {
    __shared__ unsigned short smem[4 * 128 * 64];  // 64KB: qh|ql|kh|kl, later f32 out-tile
    const int bh = blockIdx.z & 31;
    const int l0 = blockIdx.y * 128, s0 = blockIdx.x * 128;
    const int t = threadIdx.x;
    const int w = t >> 6, ln = t & 63;

    // ---- stage 64KB via global_load_lds: 4 arrays * 4 insts per wave (1KB each)
    {
        const size_t pan = (size_t)bh * NL * ND;
        const unsigned short* srcs[4] = {qbh + pan + (size_t)l0 * ND,
                                         qbl + pan + (size_t)l0 * ND,
                                         kbh + pan + (size_t)s0 * ND,
                                         kbl + pan + (size_t)s0 * ND};
#pragma unroll
        for (int arr = 0; arr < 4; ++arr) {
            const unsigned short* s = srcs[arr] + w * 2048 + ln * 8;
            unsigned short* d = smem + arr * 8192 + w * 2048;
#pragma unroll
            for (int u = 0; u < 4; ++u) {
                __builtin_amdgcn_global_load_lds((const __attribute__((address_space(1))) unsigned int*)(s + u * 512),
                                                 (__attribute__((address_space(3))) unsigned int*)(d + u * 512),
                                                 16, 0, 0);
            }
        }
    }
    __syncthreads();

    const int wr = w >> 1, wc = w & 1;
    const int fr = ln & 15, g = ln >> 4;
    const int swz = (fr & 7) << 4;
    const char* sb = (const char*)smem;

    // ---- preload all k fragments (A operand, rows s)
    short8 kh_f[4][2], kl_f[4][2];
#pragma unroll
    for (int i = 0; i < 4; ++i)
#pragma unroll
        for (int kc = 0; kc < 2; ++kc) {
            const int cofs = ((kc << 6) | (g << 4)) ^ swz;
            const int arow = wr * 64 + i * 16 + fr;
            kh_f[i][kc] = *(const short8*)(sb + 2 * 16384 + arow * 128 + cofs);
            kl_f[i][kc] = *(const short8*)(sb + 3 * 16384 + arow * 128 + cofs);
        }

    // inv_den for this lane's 4 output rows (read early, global)
    const float* invp = invden + (size_t)bh * NL + l0 + wc * 64 + fr;
    float invs[4];
#pragma unroll
    for (int j = 0; j < 4; ++j) invs[j] = invp[j * 16];

    // ---- full compute: acc[i][j] persistent (64 VGPR)
    f32x4 acc[4][4];
#pragma unroll
    for (int i = 0; i < 4; ++i)
#pragma unroll
        for (int j = 0; j < 4; ++j) acc[i][j] = (f32x4){0.f, 0.f, 0.f, 0.f};

#pragma unroll
    for (int j = 0; j < 4; ++j) {
        short8 qh_f[2], ql_f[2];
#pragma unroll
        for (int kc = 0; kc < 2; ++kc) {
            const int cofs = ((kc << 6) | (g << 4)) ^ swz;
            const int brow = wc * 64 + j * 16 + fr;
            qh_f[kc] = *(const short8*)(sb + 0 * 16384 + brow * 128 + cofs);
            ql_f[kc] = *(const short8*)(sb + 1 * 16384 + brow * 128 + cofs);
        }
#pragma unroll
        for (int i = 0; i < 4; ++i)
#pragma unroll
            for (int kc = 0; kc < 2; ++kc) {
                acc[i][j] = __builtin_amdgcn_mfma_f32_16x16x32_bf16(kh_f[i][kc], qh_f[kc], acc[i][j], 0, 0, 0);
                acc[i][j] = __builtin_amdgcn_mfma_f32_16x16x32_bf16(kh_f[i][kc], ql_f[kc], acc[i][j], 0, 0, 0);
                acc[i][j] = __builtin_amdgcn_mfma_f32_16x16x32_bf16(kl_f[i][kc], qh_f[kc], acc[i][j], 0, 0, 0);
            }
    }
    __syncthreads();  // all fragment reads done; smem is now free

    // ---- epilogue phase 1: scaled acc -> swizzled f32 LDS tile [128][128]
    // chunk index (16B units) c in row l stored at c ^ (l & 7)  -> bank-floor both phases
    float* ot = (float*)smem;
#pragma unroll
    for (int j = 0; j < 4; ++j) {
        const int l = wc * 64 + j * 16 + fr;
        const float inv = invs[j];
#pragma unroll
        for (int i = 0; i < 4; ++i) {
            const int c = wr * 16 + i * 4 + g;
            f32x4 vv = acc[i][j];
            vv[0] *= inv; vv[1] *= inv; vv[2] *= inv; vv[3] *= inv;
            *(f32x4*)&ot[l * 128 + ((c ^ (l & 7)) << 2)] = vv;
        }
    }
    __syncthreads();

    // ---- epilogue phase 2: coalesced stores, 512B contiguous per half-wave
    const int rslot = t >> 5;     // 0..7
    const int cc = t & 31;        // 16B chunk within row
#pragma unroll
    for (int u = 0; u < 16; ++u) {
        const int row = rslot + u * 8;  // 0..127
        const f32x4 vv = *(const f32x4*)&ot[row * 128 + ((cc ^ (row & 7)) << 2)];
        *(f32x4*)(out + ((size_t)bh * NL + l0 + row) * NL + s0 + cc * 4) = vv;
    }
}

extern "C" void kernel_launch(void* const* d_in, const int* in_sizes, int n_in,
                              void* d_out, int out_size, void* d_ws, size_t ws_size,
                              hipStream_t stream) {
    const float* query = (const float*)d_in[0];  // [B,L,H,D]
    const float* key   = (const float*)d_in[1];  // [B,L,H,D]
    const float* Wq    = (const float*)d_in[2];  // [H,D,D]
    const float* Wk    = (const float*)d_in[3];  // [H,D,D]
    float* out = (float*)d_out;                  // [B,H,L,S]

    const size_t npan = (size_t)NB * NH * NL * ND;  // 4.19M elems
    char* ws = (char*)d_ws;
    unsigned short* qbh = (unsigned short*)(ws);
    unsigned short* qbl = (unsigned short*)(ws + 1 * npan * 2);
    unsigned short* kbh = (unsigned short*)(ws + 2 * npan * 2);
    unsigned short* kbl = (unsigned short*)(ws + 3 * npan * 2);
    double* part  = (double*)(ws + 4 * npan * 2);                  // 512*64 f64 = 256KB
    double* v     = (double*)(ws + 4 * npan * 2 + 262144);         // 32*64 f64
    float* invden = (float*)(ws + 4 * npan * 2 + 262144 + 16384);  // 32*2048 f32

    proj_bf16_kernel<<<NB * NH * (NL / 128), 256, 0, stream>>>(query, Wq, qbh, qbl);
    proj_bf16_kernel<<<NB * NH * (NL / 128), 256, 0, stream>>>(key, Wk, kbh, kbl);
    ksum_part_kernel<<<NB * NH * 16, 256, 0, stream>>>(key, part);
    prep_kernel<<<NB * NH, 64, 0, stream>>>(part, Wq, Wk, v);
    den_kernel<<<dim3(NB * NH, NL / 256), 256, 0, stream>>>(query, v, invden);
    // DIAGNOSTIC: z = 4*32 -> 4 identical rewrites; revert to 32 next round.
    attn_kernel<<<dim3(NL / 128, NL / 128, 4 * NB * NH), 256, 0, stream>>>(qbh, qbl, kbh, kbl, invden, out);
}

// Round 10
// 206.586 us; speedup vs baseline: 3.0957x; 3.0957x over previous
//
#include <hip/hip_runtime.h>
#include <stdint.h>

#define NB 2
#define NL 2048
#define NH 16
#define ND 64
// out: [B,H,L,S] f32, S = NL

typedef __attribute__((ext_vector_type(8))) short short8;
typedef __attribute__((ext_vector_type(4))) float f32x4;
typedef __attribute__((ext_vector_type(4))) unsigned short ushort4v;

__device__ __forceinline__ unsigned short f2bf_rne(float x) {
    union { float f; unsigned int u; } v; v.f = x;
    unsigned int r = v.u + 0x7fffu + ((v.u >> 16) & 1u);
    return (unsigned short)(r >> 16);
}
__device__ __forceinline__ float bf2f(unsigned short b) {
    union { unsigned int u; float f; } v; v.u = ((unsigned int)b) << 16;
    return v.f;
}

// ---------------- Kernel A: proj + bf16 hi/lo split, head-major SWIZZLED panels
// panel store: element group of row l goes to index e ^ ((l&7)<<3) (byte ^ ((l&7)<<4))
__global__ __launch_bounds__(256) void proj_bf16_kernel(const float* __restrict__ x,
                                                        const float* __restrict__ W,
                                                        unsigned short* __restrict__ ph,
                                                        unsigned short* __restrict__ pl) {
    __shared__ float Wlds[ND * ND];   // [d][e]
    __shared__ float xs[128 * 68];    // [r][d], stride 68 floats
    const int blk = blockIdx.x;       // b*256 + h*16 + lc
    const int lc = blk & 15;
    const int h = (blk >> 4) & 15;
    const int b = blk >> 8;
    const int l0 = lc * 128;
    const int t = threadIdx.x;

    {
        const float4* src = (const float4*)(W + (size_t)h * ND * ND);
#pragma unroll
        for (int i = 0; i < 4; ++i)
            ((float4*)Wlds)[t + 256 * i] = src[t + 256 * i];
    }
    {
#pragma unroll
        for (int i = 0; i < 8; ++i) {
            const int idx = t + 256 * i;  // 0..2047
            const int r = idx >> 4, c = idx & 15;
            const float4 v = *(const float4*)(x + (((size_t)b * NL + l0 + r) * NH + h) * ND + c * 4);
            *(float4*)&xs[r * 68 + c * 4] = v;
        }
    }
    __syncthreads();

    const int e4 = (t & 15) * 4;
    const int rg = t >> 4;  // 0..15
    float acc[8][4] = {};
    for (int d = 0; d < ND; ++d) {
        const float4 w4 = *(const float4*)&Wlds[d * ND + e4];
#pragma unroll
        for (int it = 0; it < 8; ++it) {
            const float xv = xs[(rg + it * 16) * 68 + d];
            acc[it][0] += xv * w4.x; acc[it][1] += xv * w4.y;
            acc[it][2] += xv * w4.z; acc[it][3] += xv * w4.w;
        }
    }

    unsigned short* phh = ph + ((size_t)(b * NH + h) * NL + l0) * ND;
    unsigned short* pll = pl + ((size_t)(b * NH + h) * NL + l0) * ND;
#pragma unroll
    for (int it = 0; it < 8; ++it) {
        const int r = rg + it * 16;
        const int ep = e4 ^ ((r & 7) << 3);  // swizzled element position (8B-group safe)
        ushort4v hv, lv;
#pragma unroll
        for (int j = 0; j < 4; ++j) {
            const unsigned short hb = f2bf_rne(acc[it][j]);
            hv[j] = hb;
            lv[j] = f2bf_rne(acc[it][j] - bf2f(hb));
        }
        *(ushort4v*)&phh[(size_t)r * ND + ep] = hv;
        *(ushort4v*)&pll[(size_t)r * ND + ep] = lv;
    }
}

// ---------------- Kernel B: part[bh][chunk][e] = sum over 128 keys (f64, fixed order)
__global__ __launch_bounds__(256) void ksum_part_kernel(const float* __restrict__ key,
                                                        double* __restrict__ part) {
    __shared__ double red[4][64];
    const int blk = blockIdx.x;   // bh*16 + chunk
    const int chunk = blk & 15, bh = blk >> 4;
    const int b = bh >> 4, h = bh & 15;
    const int t = threadIdx.x;
    const int e = t & 63, sub = t >> 6;
    const float* base = key + ((size_t)b * NL * NH + h) * ND + e;
    double acc = 0.0;
    const int s0 = chunk * 128 + sub * 32;
    for (int s = s0; s < s0 + 32; ++s)
        acc += (double)base[(size_t)s * (NH * ND)];
    red[sub][e] = acc;
    __syncthreads();
    if (t < 64) {
        const double s2 = red[0][t] + red[1][t] + red[2][t] + red[3][t];
        part[(size_t)blk * 64 + t] = s2;
    }
}

// ---------------- Kernel C: reduce partials; v[b,h,d] = Wq . (Wk^T . xsum)  (f64)
__global__ __launch_bounds__(64) void prep_kernel(const double* __restrict__ part,
                                                  const float* __restrict__ Wq,
                                                  const float* __restrict__ Wk,
                                                  double* __restrict__ v) {
    __shared__ double xs[ND], ks[ND];
    const int bh = blockIdx.x;
    const int h = bh & 15;
    const int t = threadIdx.x;  // 0..63
    {
        double a = 0.0;
#pragma unroll
        for (int c = 0; c < 16; ++c) a += part[((size_t)bh * 16 + c) * 64 + t];
        xs[t] = a;
    }
    __syncthreads();
    {
        double acc = 0.0;
        const float* wk = Wk + (size_t)h * ND * ND + t;  // column t
        for (int d = 0; d < ND; ++d) acc += xs[d] * (double)wk[(size_t)d * ND];
        ks[t] = acc;
    }
    __syncthreads();
    {
        double acc = 0.0;
        const float* wq = Wq + (size_t)h * ND * ND + (size_t)t * ND;  // row t
        for (int e = 0; e < ND; ++e) acc += (double)wq[e] * ks[e];
        v[(size_t)bh * ND + t] = acc;
    }
}

// ---------------- Kernel D: invden[b,h,l] = 1 / (x_q . v)  (f64 exact)
__global__ __launch_bounds__(256) void den_kernel(const float* __restrict__ xq,
                                                  const double* __restrict__ v,
                                                  float* __restrict__ invden) {
    __shared__ double vs[ND];
    const int bh = blockIdx.x;
    const int b = bh >> 4, h = bh & 15;
    const int t = threadIdx.x;
    if (t < 64) vs[t] = v[(size_t)bh * ND + t];
    __syncthreads();
    const int l = blockIdx.y * 256 + t;
    const float* xp = xq + (((size_t)b * NL + l) * NH + h) * ND;
    double acc = 0.0;
#pragma unroll 8
    for (int d = 0; d < ND; ++d) acc += (double)xp[d] * vs[d];
    invden[(size_t)bh * NL + l] = (float)(1.0 / acc);
}

// ---------------- Kernel E: attn — T-F occupancy build.
// 128x128 tile, 4 waves 2x2. Only K panels (kh|kl) staged in LDS (32KB);
// Q fragments read DIRECTLY from global (L2-hot, swizzle algebra identical
// since brow&7 == fr&7). __launch_bounds__(256,4) -> target 4 blocks/CU.
__global__ __launch_bounds__(256, 4) void attn_kernel(const unsigned short* __restrict__ qbh,
                                                      const unsigned short* __restrict__ qbl,
                                                      const unsigned short* __restrict__ kbh,
                                                      const unsigned short* __restrict__ kbl,
                                                      const float* __restrict__ invden,
                                                      float* __restrict__ out) {
    __shared__ unsigned short smem[2 * 128 * 64];  // kh|kl, 16KB each, linear
    const int bh = blockIdx.z;
    const int l0 = blockIdx.y * 128, s0 = blockIdx.x * 128;
    const int t = threadIdx.x;
    const int w = t >> 6, ln = t & 63;

    // ---- stage 32KB (K panels) via global_load_lds: 2 arrays * 4 insts per wave
    {
        const size_t pan = (size_t)bh * NL * ND;
        const unsigned short* srcs[2] = {kbh + pan + (size_t)s0 * ND,
                                         kbl + pan + (size_t)s0 * ND};
#pragma unroll
        for (int arr = 0; arr < 2; ++arr) {
            const unsigned short* s = srcs[arr] + w * 2048 + ln * 8;
            unsigned short* d = smem + arr * 8192 + w * 2048;
#pragma unroll
            for (int u = 0; u < 4; ++u) {
                __builtin_amdgcn_global_load_lds((const __attribute__((address_space(1))) unsigned int*)(s + u * 512),
                                                 (__attribute__((address_space(3))) unsigned int*)(d + u * 512),
                                                 16, 0, 0);
            }
        }
    }
    __syncthreads();

    const int wr = w >> 1, wc = w & 1;
    const int fr = ln & 15, g = ln >> 4;
    const int swz = (fr & 7) << 4;
    const char* sb = (const char*)smem;
    const char* qh_pb = (const char*)(qbh + (size_t)bh * NL * ND + (size_t)l0 * ND);
    const char* ql_pb = (const char*)(qbl + (size_t)bh * NL * ND + (size_t)l0 * ND);

    // ---- preload all k fragments (A operand, rows s) from LDS
    short8 kh_f[4][2], kl_f[4][2];
#pragma unroll
    for (int i = 0; i < 4; ++i)
#pragma unroll
        for (int kc = 0; kc < 2; ++kc) {
            const int cofs = ((kc << 6) | (g << 4)) ^ swz;
            const int arow = wr * 64 + i * 16 + fr;
            kh_f[i][kc] = *(const short8*)(sb + 0 * 16384 + arow * 128 + cofs);
            kl_f[i][kc] = *(const short8*)(sb + 1 * 16384 + arow * 128 + cofs);
        }

    const float* invp = invden + (size_t)bh * NL + l0 + wc * 64 + fr;
#pragma unroll
    for (int j = 0; j < 4; ++j) {
        // q fragments for this l-quadrant column — DIRECT from global (L2-hot)
        const int brow = wc * 64 + j * 16 + fr;
        short8 qh_f[2], ql_f[2];
#pragma unroll
        for (int kc = 0; kc < 2; ++kc) {
            const int cofs = ((kc << 6) | (g << 4)) ^ swz;  // brow&7 == fr&7
            qh_f[kc] = *(const short8*)(qh_pb + brow * 128 + cofs);
            ql_f[kc] = *(const short8*)(ql_pb + brow * 128 + cofs);
        }
        const float inv = invp[j * 16];
        float* orow = out + ((size_t)bh * NL + l0 + brow) * NL + s0 + wr * 64 + g * 4;
#pragma unroll
        for (int i = 0; i < 4; ++i) {
            f32x4 a = (f32x4){0.f, 0.f, 0.f, 0.f};
#pragma unroll
            for (int kc = 0; kc < 2; ++kc) {
                a = __builtin_amdgcn_mfma_f32_16x16x32_bf16(kh_f[i][kc], qh_f[kc], a, 0, 0, 0);
                a = __builtin_amdgcn_mfma_f32_16x16x32_bf16(kh_f[i][kc], ql_f[kc], a, 0, 0, 0);
                a = __builtin_amdgcn_mfma_f32_16x16x32_bf16(kl_f[i][kc], qh_f[kc], a, 0, 0, 0);
            }
            f32x4 vv = a;
            vv[0] *= inv; vv[1] *= inv; vv[2] *= inv; vv[3] *= inv;
            *(f32x4*)(orow + i * 16) = vv;
        }
    }
}

extern "C" void kernel_launch(void* const* d_in, const int* in_sizes, int n_in,
                              void* d_out, int out_size, void* d_ws, size_t ws_size,
                              hipStream_t stream) {
    const float* query = (const float*)d_in[0];  // [B,L,H,D]
    const float* key   = (const float*)d_in[1];  // [B,L,H,D]
    const float* Wq    = (const float*)d_in[2];  // [H,D,D]
    const float* Wk    = (const float*)d_in[3];  // [H,D,D]
    float* out = (float*)d_out;                  // [B,H,L,S]

    const size_t npan = (size_t)NB * NH * NL * ND;  // 4.19M elems
    char* ws = (char*)d_ws;
    unsigned short* qbh = (unsigned short*)(ws);
    unsigned short* qbl = (unsigned short*)(ws + 1 * npan * 2);
    unsigned short* kbh = (unsigned short*)(ws + 2 * npan * 2);
    unsigned short* kbl = (unsigned short*)(ws + 3 * npan * 2);
    double* part  = (double*)(ws + 4 * npan * 2);                  // 512*64 f64 = 256KB
    double* v     = (double*)(ws + 4 * npan * 2 + 262144);         // 32*64 f64
    float* invden = (float*)(ws + 4 * npan * 2 + 262144 + 16384);  // 32*2048 f32

    proj_bf16_kernel<<<NB * NH * (NL / 128), 256, 0, stream>>>(query, Wq, qbh, qbl);
    proj_bf16_kernel<<<NB * NH * (NL / 128), 256, 0, stream>>>(key, Wk, kbh, kbl);
    ksum_part_kernel<<<NB * NH * 16, 256, 0, stream>>>(key, part);
    prep_kernel<<<NB * NH, 64, 0, stream>>>(part, Wq, Wk, v);
    den_kernel<<<dim3(NB * NH, NL / 256), 256, 0, stream>>>(query, v, invden);
    attn_kernel<<<dim3(NL / 128, NL / 128, NB * NH), 256, 0, stream>>>(qbh, qbl, kbh, kbl, invden, out);
}

// Round 11
// 189.505 us; speedup vs baseline: 3.3748x; 1.0901x over previous
//
#include <hip/hip_runtime.h>
#include <stdint.h>

#define NB 2
#define NL 2048
#define NH 16
#define ND 64
// out: [B,H,L,S] f32, S = NL

typedef __attribute__((ext_vector_type(8))) short short8;
typedef __attribute__((ext_vector_type(4))) float f32x4;
typedef __attribute__((ext_vector_type(4))) unsigned short ushort4v;

__device__ __forceinline__ unsigned short f2bf_rne(float x) {
    union { float f; unsigned int u; } v; v.f = x;
    unsigned int r = v.u + 0x7fffu + ((v.u >> 16) & 1u);
    return (unsigned short)(r >> 16);
}
__device__ __forceinline__ float bf2f(unsigned short b) {
    union { unsigned int u; float f; } v; v.u = ((unsigned int)b) << 16;
    return v.f;
}

// ---------------- Kernel PRE: fused proj-q | proj-k | ksum partials
// blocks 0..511: proj query -> qbh/qbl ; 512..1023: proj key -> kbh/kbl ;
// 1024..1535: ksum partials (f64, fixed order).
// Panel store swizzle: 4-elem group at e4 goes to e4 ^ ((row&7)<<3).
__global__ __launch_bounds__(256) void pre_kernel(const float* __restrict__ query,
                                                  const float* __restrict__ key,
                                                  const float* __restrict__ Wq,
                                                  const float* __restrict__ Wk,
                                                  unsigned short* __restrict__ qbh,
                                                  unsigned short* __restrict__ qbl,
                                                  unsigned short* __restrict__ kbh,
                                                  unsigned short* __restrict__ kbl,
                                                  double* __restrict__ part) {
    __shared__ __align__(16) char lds_raw[16384 + 34816];  // Wlds | xs
    const int blk = blockIdx.x;
    const int t = threadIdx.x;

    if (blk < 1024) {
        // ---- projection path
        const bool isq = blk < 512;
        const int pb = isq ? blk : blk - 512;
        const float* x = isq ? query : key;
        const float* W = isq ? Wq : Wk;
        unsigned short* ph = isq ? qbh : kbh;
        unsigned short* pl = isq ? qbl : kbl;
        float* Wlds = (float*)lds_raw;                 // [d][e] 16KB
        float* xs = (float*)(lds_raw + 16384);         // [r][d] stride 68

        const int lc = pb & 15;
        const int h = (pb >> 4) & 15;
        const int b = pb >> 8;
        const int l0 = lc * 128;

        {
            const float4* src = (const float4*)(W + (size_t)h * ND * ND);
#pragma unroll
            for (int i = 0; i < 4; ++i)
                ((float4*)Wlds)[t + 256 * i] = src[t + 256 * i];
        }
        {
#pragma unroll
            for (int i = 0; i < 8; ++i) {
                const int idx = t + 256 * i;  // 0..2047
                const int r = idx >> 4, c = idx & 15;
                const float4 v = *(const float4*)(x + (((size_t)b * NL + l0 + r) * NH + h) * ND + c * 4);
                *(float4*)&xs[r * 68 + c * 4] = v;
            }
        }
        __syncthreads();

        const int e4 = (t & 15) * 4;
        const int rg = t >> 4;  // 0..15
        float acc[8][4] = {};
        for (int d = 0; d < ND; ++d) {
            const float4 w4 = *(const float4*)&Wlds[d * ND + e4];
#pragma unroll
            for (int it = 0; it < 8; ++it) {
                const float xv = xs[(rg + it * 16) * 68 + d];
                acc[it][0] += xv * w4.x; acc[it][1] += xv * w4.y;
                acc[it][2] += xv * w4.z; acc[it][3] += xv * w4.w;
            }
        }

        unsigned short* phh = ph + ((size_t)(b * NH + h) * NL + l0) * ND;
        unsigned short* pll = pl + ((size_t)(b * NH + h) * NL + l0) * ND;
#pragma unroll
        for (int it = 0; it < 8; ++it) {
            const int r = rg + it * 16;
            const int ep = e4 ^ ((r & 7) << 3);
            ushort4v hv, lv;
#pragma unroll
            for (int j = 0; j < 4; ++j) {
                const unsigned short hb = f2bf_rne(acc[it][j]);
                hv[j] = hb;
                lv[j] = f2bf_rne(acc[it][j] - bf2f(hb));
            }
            *(ushort4v*)&phh[(size_t)r * ND + ep] = hv;
            *(ushort4v*)&pll[(size_t)r * ND + ep] = lv;
        }
    } else {
        // ---- ksum partials path (identical arithmetic/order to R7)
        double (*red)[64] = (double(*)[64])lds_raw;
        const int blk2 = blk - 1024;  // bh*16 + chunk
        const int chunk = blk2 & 15, bh = blk2 >> 4;
        const int b = bh >> 4, h = bh & 15;
        const int e = t & 63, sub = t >> 6;
        const float* base = key + ((size_t)b * NL * NH + h) * ND + e;
        double acc = 0.0;
        const int s0 = chunk * 128 + sub * 32;
        for (int s = s0; s < s0 + 32; ++s)
            acc += (double)base[(size_t)s * (NH * ND)];
        red[sub][e] = acc;
        __syncthreads();
        if (t < 64) {
            const double s2 = red[0][t] + red[1][t] + red[2][t] + red[3][t];
            part[(size_t)blk2 * 64 + t] = s2;
        }
    }
}

// ---------------- Kernel C: reduce partials; v[b,h,d] = Wq . (Wk^T . xsum)  (f64)
__global__ __launch_bounds__(64) void prep_kernel(const double* __restrict__ part,
                                                  const float* __restrict__ Wq,
                                                  const float* __restrict__ Wk,
                                                  double* __restrict__ v) {
    __shared__ double xs[ND], ks[ND];
    const int bh = blockIdx.x;
    const int h = bh & 15;
    const int t = threadIdx.x;  // 0..63
    {
        double a = 0.0;
#pragma unroll
        for (int c = 0; c < 16; ++c) a += part[((size_t)bh * 16 + c) * 64 + t];
        xs[t] = a;
    }
    __syncthreads();
    {
        double acc = 0.0;
        const float* wk = Wk + (size_t)h * ND * ND + t;  // column t
        for (int d = 0; d < ND; ++d) acc += xs[d] * (double)wk[(size_t)d * ND];
        ks[t] = acc;
    }
    __syncthreads();
    {
        double acc = 0.0;
        const float* wq = Wq + (size_t)h * ND * ND + (size_t)t * ND;  // row t
        for (int e = 0; e < ND; ++e) acc += (double)wq[e] * ks[e];
        v[(size_t)bh * ND + t] = acc;
    }
}

// ---------------- Kernel D: invden[b,h,l] = 1 / (x_q . v)  (f64 exact)
__global__ __launch_bounds__(256) void den_kernel(const float* __restrict__ xq,
                                                  const double* __restrict__ v,
                                                  float* __restrict__ invden) {
    __shared__ double vs[ND];
    const int bh = blockIdx.x;
    const int b = bh >> 4, h = bh & 15;
    const int t = threadIdx.x;
    if (t < 64) vs[t] = v[(size_t)bh * ND + t];
    __syncthreads();
    const int l = blockIdx.y * 256 + t;
    const float* xp = xq + (((size_t)b * NL + l) * NH + h) * ND;
    double acc = 0.0;
#pragma unroll 8
    for (int d = 0; d < ND; ++d) acc += (double)xp[d] * vs[d];
    invden[(size_t)bh * NL + l] = (float)(1.0 / acc);
}

// ---------------- Kernel E: attn — continuous-issue build.
// Block fixes (bh, s0): K panels staged to LDS ONCE (32KB), single barrier,
// then 4 l-tiles of pure compute+store (no further barriers -> stores never
// drained mid-kernel). Q frags loaded from global once per TILE (amortized).
// 4 waves 2x2 per 128x128 tile; swapped operands; 4 blocks/CU target.
__global__ __launch_bounds__(256, 4) void attn_kernel(const unsigned short* __restrict__ qbh,
                                                      const unsigned short* __restrict__ qbl,
                                                      const unsigned short* __restrict__ kbh,
                                                      const unsigned short* __restrict__ kbl,
                                                      const float* __restrict__ invden,
                                                      float* __restrict__ out) {
    __shared__ unsigned short smem[2 * 128 * 64];  // kh|kl, 16KB each, linear
    const int lg = blockIdx.x;           // l-group 0..3 (4 tiles each)
    const int s0 = blockIdx.y * 128;
    const int bh = blockIdx.z;
    const int t = threadIdx.x;
    const int w = t >> 6, ln = t & 63;

    // ---- stage K panels once: 2 arrays * 4 insts per wave (1KB each)
    {
        const size_t pan = (size_t)bh * NL * ND;
        const unsigned short* srcs[2] = {kbh + pan + (size_t)s0 * ND,
                                         kbl + pan + (size_t)s0 * ND};
#pragma unroll
        for (int arr = 0; arr < 2; ++arr) {
            const unsigned short* s = srcs[arr] + w * 2048 + ln * 8;
            unsigned short* d = smem + arr * 8192 + w * 2048;
#pragma unroll
            for (int u = 0; u < 4; ++u) {
                __builtin_amdgcn_global_load_lds((const __attribute__((address_space(1))) unsigned int*)(s + u * 512),
                                                 (__attribute__((address_space(3))) unsigned int*)(d + u * 512),
                                                 16, 0, 0);
            }
        }
    }
    __syncthreads();  // the ONLY barrier

    const int wr = w >> 1, wc = w & 1;
    const int fr = ln & 15, g = ln >> 4;
    const int swz = (fr & 7) << 4;
    const int cofs0 = (g << 4) ^ swz;
    const int cofs1 = (64 | (g << 4)) ^ swz;
    const char* sb = (const char*)smem;
    const char* qh_pb = (const char*)(qbh + (size_t)bh * NL * ND);
    const char* ql_pb = (const char*)(qbl + (size_t)bh * NL * ND);

    for (int tile = 0; tile < 4; ++tile) {
        const int l0 = lg * 512 + tile * 128;
        const int lbase = l0 + wc * 64 + fr;

        // all q fragments for this tile, direct from L2-hot panels (16 loads)
        short8 qh_f[4][2], ql_f[4][2];
#pragma unroll
        for (int j = 0; j < 4; ++j) {
            const size_t roff = (size_t)(lbase + j * 16) * 128;  // (row&7)==(fr&7)
            qh_f[j][0] = *(const short8*)(qh_pb + roff + cofs0);
            qh_f[j][1] = *(const short8*)(qh_pb + roff + cofs1);
            ql_f[j][0] = *(const short8*)(ql_pb + roff + cofs0);
            ql_f[j][1] = *(const short8*)(ql_pb + roff + cofs1);
        }
        const float* invp = invden + (size_t)bh * NL + lbase;
        float invs[4];
#pragma unroll
        for (int j = 0; j < 4; ++j) invs[j] = invp[j * 16];

#pragma unroll
        for (int i = 0; i < 4; ++i) {
            const int arow = wr * 64 + i * 16 + fr;
            const short8 kh0 = *(const short8*)(sb + arow * 128 + cofs0);
            const short8 kh1 = *(const short8*)(sb + arow * 128 + cofs1);
            const short8 kl0 = *(const short8*)(sb + 16384 + arow * 128 + cofs0);
            const short8 kl1 = *(const short8*)(sb + 16384 + arow * 128 + cofs1);
#pragma unroll
            for (int j = 0; j < 4; ++j) {
                f32x4 a = (f32x4){0.f, 0.f, 0.f, 0.f};
                a = __builtin_amdgcn_mfma_f32_16x16x32_bf16(kh0, qh_f[j][0], a, 0, 0, 0);
                a = __builtin_amdgcn_mfma_f32_16x16x32_bf16(kh0, ql_f[j][0], a, 0, 0, 0);
                a = __builtin_amdgcn_mfma_f32_16x16x32_bf16(kl0, qh_f[j][0], a, 0, 0, 0);
                a = __builtin_amdgcn_mfma_f32_16x16x32_bf16(kh1, qh_f[j][1], a, 0, 0, 0);
                a = __builtin_amdgcn_mfma_f32_16x16x32_bf16(kh1, ql_f[j][1], a, 0, 0, 0);
                a = __builtin_amdgcn_mfma_f32_16x16x32_bf16(kl1, qh_f[j][1], a, 0, 0, 0);
                const float inv = invs[j];
                f32x4 vv = a;
                vv[0] *= inv; vv[1] *= inv; vv[2] *= inv; vv[3] *= inv;
                *(f32x4*)(out + ((size_t)bh * NL + lbase + j * 16) * NL + s0 + wr * 64 + g * 4 + i * 16) = vv;
            }
        }
    }
}

extern "C" void kernel_launch(void* const* d_in, const int* in_sizes, int n_in,
                              void* d_out, int out_size, void* d_ws, size_t ws_size,
                              hipStream_t stream) {
    const float* query = (const float*)d_in[0];  // [B,L,H,D]
    const float* key   = (const float*)d_in[1];  // [B,L,H,D]
    const float* Wq    = (const float*)d_in[2];  // [H,D,D]
    const float* Wk    = (const float*)d_in[3];  // [H,D,D]
    float* out = (float*)d_out;                  // [B,H,L,S]

    const size_t npan = (size_t)NB * NH * NL * ND;  // 4.19M elems
    char* ws = (char*)d_ws;
    unsigned short* qbh = (unsigned short*)(ws);
    unsigned short* qbl = (unsigned short*)(ws + 1 * npan * 2);
    unsigned short* kbh = (unsigned short*)(ws + 2 * npan * 2);
    unsigned short* kbl = (unsigned short*)(ws + 3 * npan * 2);
    double* part  = (double*)(ws + 4 * npan * 2);                  // 512*64 f64 = 256KB
    double* v     = (double*)(ws + 4 * npan * 2 + 262144);         // 32*64 f64
    float* invden = (float*)(ws + 4 * npan * 2 + 262144 + 16384);  // 32*2048 f32

    pre_kernel<<<1536, 256, 0, stream>>>(query, key, Wq, Wk, qbh, qbl, kbh, kbl, part);
    prep_kernel<<<NB * NH, 64, 0, stream>>>(part, Wq, Wk, v);
    den_kernel<<<dim3(NB * NH, NL / 256), 256, 0, stream>>>(query, v, invden);
    attn_kernel<<<dim3(4, 16, NB * NH), 256, 0, stream>>>(qbh, qbl, kbh, kbl, invden, out);
}